// Round 2
// baseline (628.250 us; speedup 1.0000x reference)
//
#include <hip/hip_runtime.h>
#include <hip/hip_bf16.h>

#define D 128
#define CH 4096   // edges per block in CSR partition passes
#define BM 32     // dst rows per fused block (2 waves x 16 rows)

typedef unsigned int u32;
typedef unsigned short u16;
typedef __attribute__((ext_vector_type(8))) short s16x8;
typedef __attribute__((ext_vector_type(4))) float f32x4;
typedef __attribute__((ext_vector_type(2))) float f32x2;

__device__ __forceinline__ float bf2f(u16 u) {
    union { u32 u; float f; } v; v.u = ((u32)u) << 16; return v.f;
}
__device__ __forceinline__ u16 f2bf(float f) {
    union { float f; u32 u; } v; v.f = f;
    return (u16)((v.u + 0x7fffu + ((v.u >> 16) & 1u)) >> 16);
}
__device__ __forceinline__ u32 pack_bf2(float a, float b) {
    __hip_bfloat162 t = __float22bfloat162_rn(make_float2(a, b));
    union { __hip_bfloat162 t; u32 u; } v; v.t = t; return v.u;
}
__device__ __forceinline__ void unpack2(u32 u, float& lo, float& hi) {
    union { u32 u; float f; } a, b;
    a.u = u << 16; b.u = u & 0xffff0000u;
    lo = a.f; hi = b.f;
}

// ---- dtype detector (also zeroes gcnt for the CSR build) ----
__global__ void detect_dtype(const u16* __restrict__ x, int* __restrict__ flag,
                             int* __restrict__ gcnt, int nbuck) {
    __shared__ int cnt;
    if (threadIdx.x == 0) cnt = 0;
    __syncthreads();
    if ((int)threadIdx.x < nbuck) gcnt[threadIdx.x] = 0;
    u16 u = x[2 * threadIdx.x];
    int e = (u >> 7) & 0xFF;
    if (e >= 96 && e <= 150) atomicAdd(&cnt, 1);
    __syncthreads();
    if (threadIdx.x == 0) *flag = (cnt >= 128) ? 0 : 1;
}

// ---- canonicalize (body only runs when inputs are fp32) ----
__global__ __launch_bounds__(256)
void to_bf16_all(const void* __restrict__ s0, const void* __restrict__ s1,
                 const void* __restrict__ s2, const void* __restrict__ s3,
                 const void* __restrict__ s4, const void* __restrict__ s5,
                 const void* __restrict__ s6,
                 u16* __restrict__ d0, u16* __restrict__ d1, u16* __restrict__ d2,
                 u16* __restrict__ d3, u16* __restrict__ d4, u16* __restrict__ d5,
                 u16* __restrict__ d6,
                 long long n0, long long n1, long long n2, long long n3,
                 long long n4, long long n5, long long n6,
                 const int* __restrict__ flag)
{
    if (*flag == 0) return;
    long long i = (long long)blockIdx.x * 256 + threadIdx.x;
    const void* s; u16* d; long long off;
    if      (i < n0)                   { s = s0; d = d0; off = i; }
    else if (i < n0+n1)                { s = s1; d = d1; off = i-n0; }
    else if (i < n0+n1+n2)             { s = s2; d = d2; off = i-n0-n1; }
    else if (i < n0+n1+n2+n3)          { s = s3; d = d3; off = i-n0-n1-n2; }
    else if (i < n0+n1+n2+n3+n4)       { s = s4; d = d4; off = i-n0-n1-n2-n3; }
    else if (i < n0+n1+n2+n3+n4+n5)    { s = s5; d = d5; off = i-n0-n1-n2-n3-n4; }
    else if (i < n0+n1+n2+n3+n4+n5+n6) { s = s6; d = d6; off = i-n0-n1-n2-n3-n4-n5; }
    else return;
    d[off] = f2bf(((const float*)s)[off]);
}

// ==== bucketed CSR build: bucket = dst>>8 (needs N<=65536, src<2^16) ====
__global__ __launch_bounds__(256)
void csr_count(const int* __restrict__ dst, int* __restrict__ gcnt, int E, int nbuck) {
    __shared__ int scnt[256];
    int tid = threadIdx.x;
    scnt[tid] = 0;
    __syncthreads();
    int base = blockIdx.x * CH;
#pragma unroll
    for (int it = 0; it < CH / 256; ++it) {
        int e = base + it * 256 + tid;
        if (e < E) atomicAdd(&scnt[dst[e] >> 8], 1);
    }
    __syncthreads();
    if (tid < nbuck && scnt[tid] > 0) atomicAdd(&gcnt[tid], scnt[tid]);
}

__global__ __launch_bounds__(256)
void csr_scan(const int* __restrict__ gcnt, int* __restrict__ bstart, int* __restrict__ bcur,
              int nbuck, int N_, int E_, int* __restrict__ offs) {
    __shared__ int wpart[4];
    int tid = threadIdx.x, lane = tid & 63, wid = tid >> 6;
    int v = (tid < nbuck) ? gcnt[tid] : 0;
    int s = v;
#pragma unroll
    for (int off = 1; off < 64; off <<= 1) {
        int t = __shfl_up(s, off, 64);
        if (lane >= off) s += t;
    }
    if (lane == 63) wpart[wid] = s;
    __syncthreads();
    int add = 0;
    for (int w = 0; w < wid; ++w) add += wpart[w];
    int excl = add + s - v;
    if (tid <= nbuck) bstart[tid] = excl;
    if (tid < nbuck)  bcur[tid]  = excl;
    if (tid == 0) offs[N_] = E_;
}

// partition edges into bucket-contiguous ebuf; rec = (dst&255)<<24 | (et<<16) | src
__global__ __launch_bounds__(256)
void csr_part(const int* __restrict__ src, const int* __restrict__ dst,
              const int* __restrict__ et, int* __restrict__ bcur,
              u32* __restrict__ ebuf, int E, int N, int nbuck) {
    __shared__ int scnt[256], sbase[256];
    int tid = threadIdx.x;
    scnt[tid] = 0;
    __syncthreads();
    int base = blockIdx.x * CH;
#pragma unroll
    for (int it = 0; it < CH / 256; ++it) {
        int e = base + it * 256 + tid;
        if (e < E) atomicAdd(&scnt[dst[e] >> 8], 1);
    }
    __syncthreads();
    if (tid < nbuck) {
        int c = scnt[tid];
        sbase[tid] = c ? atomicAdd(&bcur[tid], c) : 0;
    }
    __syncthreads();
    scnt[tid] = 0;
    __syncthreads();
#pragma unroll
    for (int it = 0; it < CH / 256; ++it) {
        int e = base + it * 256 + tid;
        if (e >= E) continue;
        int d = dst[e];
        int b = d >> 8;
        int p = sbase[b] + atomicAdd(&scnt[b], 1);
        ebuf[p] = ((u32)(d & 255) << 24) | ((u32)et[e] << 16) | (u32)src[e];
    }
}

// one block per bucket: 256-bin dstlo counting sort -> offs + rowidx ((et<<16)|src)
__global__ __launch_bounds__(256)
void csr_emit(const u32* __restrict__ ebuf, const int* __restrict__ bstart,
              int* __restrict__ offs, int* __restrict__ rowidx, int N) {
    __shared__ int hist[256], excl[256], cur[256];
    __shared__ int wpart[4];
    int b = blockIdx.x, tid = threadIdx.x;
    int lo = bstart[b], hi = bstart[b + 1];
    hist[tid] = 0; cur[tid] = 0;
    __syncthreads();
    for (int i = lo + tid; i < hi; i += 256) atomicAdd(&hist[ebuf[i] >> 24], 1);
    __syncthreads();
    int lane = tid & 63, wid = tid >> 6;
    int v = hist[tid], s = v;
#pragma unroll
    for (int off = 1; off < 64; off <<= 1) {
        int t = __shfl_up(s, off, 64);
        if (lane >= off) s += t;
    }
    if (lane == 63) wpart[wid] = s;
    __syncthreads();
    int add = 0;
    for (int w = 0; w < wid; ++w) add += wpart[w];
    int e_ = add + s - v;
    excl[tid] = e_;
    int node = (b << 8) + tid;
    if (node < N) offs[node] = lo + e_;
    __syncthreads();
    for (int i = lo + tid; i < hi; i += 256) {
        u32 rec = ebuf[i];
        int dl = rec >> 24;
        int p = lo + excl[dl] + atomicAdd(&cur[dl], 1);
        rowidx[p] = (int)(rec & 0xFFFFFFu);
    }
}

// per-edge accumulate: et-switch (wave-uniform scalar), static acc indices
#define ACC8(et_, u_) do { float l_, h_; unpack2((u_), l_, h_);        \
    switch (et_) {                                                     \
    case 0: aL[0] += l_; aH[0] += h_; break;                           \
    case 1: aL[1] += l_; aH[1] += h_; break;                           \
    case 2: aL[2] += l_; aH[2] += h_; break;                           \
    case 3: aL[3] += l_; aH[3] += h_; break;                           \
    case 4: aL[4] += l_; aH[4] += h_; break;                           \
    case 5: aL[5] += l_; aH[5] += h_; break;                           \
    case 6: aL[6] += l_; aH[6] += h_; break;                           \
    default: aL[7] += l_; aH[7] += h_; break; } } while (0)

// ==== fused layer: per 32-row dst block ====
// Phase 1 (gather): each wave owns 16 rows; per row, accumulate per-relation sums
//   in f32 VGPRs (full wave = 128 feats; edge indices broadcast via readlane),
//   round once to bf16, write to LDS plane [rel][row][128] with XOR chunk swizzle.
// Phase 2 (MFMA):  C[32x128] = sum_c planes[c] @ W_c + self @ loopW  (K = (R+1)*128),
//   self plane staged by global_load_lds with pre-swizzled global source.
// mode 0: +bias, relu, bf16 out.  mode 1: +bias, row L2-normalize, out (f32 or bf16).
__global__ __launch_bounds__(128)
void rel_layer_fused(const u16* __restrict__ xc, const u16* __restrict__ xo,
                     const int* __restrict__ offs, const int* __restrict__ rowidx,
                     const u16* __restrict__ Wc, const u16* __restrict__ Wo,
                     const u16* __restrict__ lWc, const u16* __restrict__ lWo,
                     const u16* __restrict__ bc, const u16* __restrict__ bo,
                     const int* __restrict__ flag,
                     int M, int R_, int mode, void* __restrict__ out)
{
    __shared__ u16 As[9 * BM * D];   // 73728 B: planes 0..7 = relations, 8 = self
    const bool f = (*flag != 0);
    const u16* X     = f ? xc : xo;
    const u16* Wall  = f ? Wc : Wo;
    const u16* loopW = f ? lWc : lWo;
    const u16* bias  = f ? bc : bo;

    const int row0 = blockIdx.x * BM;
    const int tid  = threadIdx.x;
    const int lane = tid & 63;
    const int wv   = tid >> 6;        // 0..1
    const int quad = lane >> 4;
    const int l16  = lane & 15;

    // ---- stage self plane early (overlaps gather; drained by the barrier) ----
    {
        auto* lds0 = (__attribute__((address_space(3))) char*)As;
#pragma unroll
        for (int it = 0; it < 4; ++it) {
            int rl = it * 8 + wv * 4 + quad;          // block-local row 0..31
            int cg = l16 ^ (rl & 15);                 // pre-swizzled source chunk
            int rg = row0 + rl; if (rg >= M) rg = M - 1;
            const u16* gp = X + (size_t)rg * D + cg * 8;
            __builtin_amdgcn_global_load_lds(
                (const __attribute__((address_space(1))) void*)gp,
                (__attribute__((address_space(3))) void*)(lds0 + 65536 + (it * 8 + wv * 4) * 256),
                16, 0, 0);
        }
    }

    // ---- gather phase ----
    {
        const u32* xr = (const u32*)X;                // row stride 64 u32
        const int gbase = row0 + wv * 16;
        int idx = gbase + lane; if (idx > M) idx = M; // offs has M+1 entries
        int offv = offs[idx];
        u32* plane = (u32*)As;

        for (int rr = 0; rr < 16; ++rr) {
            int j0 = __builtin_amdgcn_readlane(offv, rr);
            int j1 = __builtin_amdgcn_readlane(offv, rr + 1);
            float aL[8] = {0.f,0.f,0.f,0.f,0.f,0.f,0.f,0.f};
            float aH[8] = {0.f,0.f,0.f,0.f,0.f,0.f,0.f,0.f};
            int nE = j1 - j0;
            if (nE > 0) {
                int vcl = j0 + lane; if (vcl > j1 - 1) vcl = j1 - 1;
                int vrow = rowidx[vcl];               // one vector load covers <=64 edges
                int nb = nE < 64 ? nE : 64;
                int kk = 0;
                for (; kk + 8 <= nb; kk += 8) {       // 8 gathers in flight
                    int i0 = __builtin_amdgcn_readlane(vrow, kk + 0);
                    int i1 = __builtin_amdgcn_readlane(vrow, kk + 1);
                    int i2 = __builtin_amdgcn_readlane(vrow, kk + 2);
                    int i3 = __builtin_amdgcn_readlane(vrow, kk + 3);
                    int i4 = __builtin_amdgcn_readlane(vrow, kk + 4);
                    int i5 = __builtin_amdgcn_readlane(vrow, kk + 5);
                    int i6 = __builtin_amdgcn_readlane(vrow, kk + 6);
                    int i7 = __builtin_amdgcn_readlane(vrow, kk + 7);
                    u32 g0 = xr[(size_t)(i0 & 0xffff) * 64 + lane];
                    u32 g1 = xr[(size_t)(i1 & 0xffff) * 64 + lane];
                    u32 g2 = xr[(size_t)(i2 & 0xffff) * 64 + lane];
                    u32 g3 = xr[(size_t)(i3 & 0xffff) * 64 + lane];
                    u32 g4 = xr[(size_t)(i4 & 0xffff) * 64 + lane];
                    u32 g5 = xr[(size_t)(i5 & 0xffff) * 64 + lane];
                    u32 g6 = xr[(size_t)(i6 & 0xffff) * 64 + lane];
                    u32 g7 = xr[(size_t)(i7 & 0xffff) * 64 + lane];
                    ACC8(i0 >> 16, g0); ACC8(i1 >> 16, g1);
                    ACC8(i2 >> 16, g2); ACC8(i3 >> 16, g3);
                    ACC8(i4 >> 16, g4); ACC8(i5 >> 16, g5);
                    ACC8(i6 >> 16, g6); ACC8(i7 >> 16, g7);
                }
                for (; kk < nb; ++kk) {
                    int v = __builtin_amdgcn_readlane(vrow, kk);
                    u32 g = xr[(size_t)(v & 0xffff) * 64 + lane];
                    ACC8(v >> 16, g);
                }
                for (int j = j0 + 64; j < j1; ++j) {  // rare: degree > 64
                    int v = __builtin_amdgcn_readfirstlane(rowidx[j]);
                    u32 g = xr[(size_t)(v & 0xffff) * 64 + lane];
                    ACC8(v >> 16, g);
                }
            }
            // write bf16 planes, swizzled: logical chunk (lane>>2) at slot (lane>>2)^ (row&15)
            int rl = wv * 16 + rr;
            int widx = rl * 64 + (((lane >> 2) ^ rr) << 2) + (lane & 3);
#pragma unroll
            for (int r = 0; r < 8; ++r)
                if (r < R_) plane[r * 2048 + widx] = pack_bf2(aL[r], aH[r]);
        }
    }

    __syncthreads();

    // ---- MFMA phase: each wave computes 32 rows x 64 cols ----
    f32x4 acc[2][4];   // [mt][g*2+parity]
#pragma unroll
    for (int mt = 0; mt < 2; ++mt)
#pragma unroll
        for (int q = 0; q < 4; ++q) acc[mt][q] = (f32x4)0.f;

    for (int c = 0; c <= R_; ++c) {
        const u16* B = (c < R_) ? (Wall + (size_t)c * D * D) : loopW;
        const int pidx = (c < R_) ? c : 8;
        s16x8 bfr[4][4];
#pragma unroll
        for (int ks = 0; ks < 4; ++ks)
#pragma unroll
            for (int g = 0; g < 2; ++g)
#pragma unroll
                for (int jj = 0; jj < 8; ++jj) {
                    u32 p = *(const u32*)(B + (ks * 32 + quad * 8 + jj) * D + wv * 64 + g * 32 + 2 * l16);
                    bfr[ks][2 * g][jj]     = (short)(p & 0xffffu);
                    bfr[ks][2 * g + 1][jj] = (short)(p >> 16);
                }
#pragma unroll
        for (int ks = 0; ks < 4; ++ks) {
            const int chp = (ks * 4 + quad) ^ l16;
#pragma unroll
            for (int mt = 0; mt < 2; ++mt) {
                s16x8 a = *(const s16x8*)(As + (pidx * BM + mt * 16 + l16) * D + chp * 8);
#pragma unroll
                for (int q = 0; q < 4; ++q)
                    acc[mt][q] = __builtin_amdgcn_mfma_f32_16x16x32_bf16(a, bfr[ks][q], acc[mt][q], 0, 0, 0);
            }
        }
    }

    const int cp0 = wv * 32 + l16;
    const int cp1 = wv * 32 + 16 + l16;
    const float b00 = bf2f(bias[2 * cp0]), b01 = bf2f(bias[2 * cp0 + 1]);
    const float b10 = bf2f(bias[2 * cp1]), b11 = bf2f(bias[2 * cp1 + 1]);

    if (mode == 0) {
        u32* o = (u32*)out;
#pragma unroll
        for (int mt = 0; mt < 2; ++mt)
#pragma unroll
            for (int i = 0; i < 4; ++i) {
                int r = row0 + mt * 16 + quad * 4 + i;
                if (r >= M) continue;
                o[(size_t)r * 64 + cp0] = pack_bf2(fmaxf(acc[mt][0][i] + b00, 0.f),
                                                  fmaxf(acc[mt][1][i] + b01, 0.f));
                o[(size_t)r * 64 + cp1] = pack_bf2(fmaxf(acc[mt][2][i] + b10, 0.f),
                                                  fmaxf(acc[mt][3][i] + b11, 0.f));
            }
    } else {
        float* fs = (float*)As;
        __syncthreads();   // all plane reads done; LDS reusable as scratch
        float pr[2][4];
#pragma unroll
        for (int mt = 0; mt < 2; ++mt)
#pragma unroll
            for (int i = 0; i < 4; ++i) {
                float a0 = acc[mt][0][i] + b00;
                float a1 = acc[mt][1][i] + b01;
                float a2 = acc[mt][2][i] + b10;
                float a3 = acc[mt][3][i] + b11;
                acc[mt][0][i] = a0; acc[mt][1][i] = a1;
                acc[mt][2][i] = a2; acc[mt][3][i] = a3;
                float p = a0 * a0 + a1 * a1 + a2 * a2 + a3 * a3;
                p += __shfl_xor(p, 1, 64);
                p += __shfl_xor(p, 2, 64);
                p += __shfl_xor(p, 4, 64);
                p += __shfl_xor(p, 8, 64);
                pr[mt][i] = p;    // partial over this wave's 64 cols
            }
        if (l16 == 0) {
#pragma unroll
            for (int mt = 0; mt < 2; ++mt)
#pragma unroll
                for (int i = 0; i < 4; ++i)
                    fs[(mt * 16 + quad * 4 + i) * 2 + wv] = pr[mt][i];
        }
        __syncthreads();
#pragma unroll
        for (int mt = 0; mt < 2; ++mt)
#pragma unroll
            for (int i = 0; i < 4; ++i) {
                int rl = mt * 16 + quad * 4 + i;
                int r = row0 + rl;
                if (r >= M) continue;
                float sc = 1.f / fmaxf(sqrtf(fs[rl * 2] + fs[rl * 2 + 1]), 1e-12f);
                float a0 = acc[mt][0][i] * sc, a1 = acc[mt][1][i] * sc;
                float a2 = acc[mt][2][i] * sc, a3 = acc[mt][3][i] * sc;
                if (f) {
                    f32x2 w0; w0[0] = a0; w0[1] = a1;
                    f32x2 w1; w1[0] = a2; w1[1] = a3;
                    ((f32x2*)out)[(size_t)r * 64 + cp0] = w0;
                    ((f32x2*)out)[(size_t)r * 64 + cp1] = w1;
                } else {
                    ((u32*)out)[(size_t)r * 64 + cp0] = pack_bf2(a0, a1);
                    ((u32*)out)[(size_t)r * 64 + cp1] = pack_bf2(a2, a3);
                }
            }
    }
}

static inline size_t align256(size_t x) { return (x + 255) & ~(size_t)255; }

extern "C" void kernel_launch(void* const* d_in, const int* in_sizes, int n_in,
                              void* d_out, int out_size, void* d_ws, size_t ws_size,
                              hipStream_t stream)
{
    const void* x_in   = d_in[0];
    const void* W1_in  = d_in[1];
    const void* lW1_in = d_in[2];
    const void* b1_in  = d_in[3];
    const void* W2_in  = d_in[4];
    const void* lW2_in = d_in[5];
    const void* b2_in  = d_in[6];
    const int* src = (const int*)d_in[7];
    const int* dst = (const int*)d_in[8];
    const int* et  = (const int*)d_in[9];

    const int N = in_sizes[0] / D;            // 50000
    const int E = in_sizes[7];                // 800000
    const int R = in_sizes[1] / (D * D);      // 8
    const int nbuck = (N + 255) >> 8;         // 196

    const long long ND  = (long long)N * D;
    const long long RDD = (long long)R * D * D;
    const long long DDl = (long long)D * D;

    size_t off = 0;
    auto alloc = [&](size_t bytes) { size_t o = off; off = align256(off + bytes); return o; };
    size_t o_flag = alloc(256);
    size_t o_xc   = alloc((size_t)ND * 2);
    size_t o_W1   = alloc((size_t)RDD * 2);
    size_t o_lW1  = alloc((size_t)DDl * 2);
    size_t o_b1   = alloc((size_t)D * 2);
    size_t o_W2   = alloc((size_t)RDD * 2);
    size_t o_lW2  = alloc((size_t)DDl * 2);
    size_t o_b2   = alloc((size_t)D * 2);
    size_t o_h    = alloc((size_t)ND * 2);
    size_t o_offs = alloc((size_t)(N + 1) * 4);
    size_t o_gcnt = alloc(1024);
    size_t o_bst  = alloc(1040 * 4);
    size_t o_bcur = alloc(1024);
    size_t o_ebuf = alloc((size_t)E * 4);
    size_t o_ridx = alloc((size_t)E * 4);
    (void)ws_size;

    char* ws = (char*)d_ws;
    int* flag   = (int*)(ws + o_flag);
    u16* x_c    = (u16*)(ws + o_xc);
    u16* W1c    = (u16*)(ws + o_W1);
    u16* lW1c   = (u16*)(ws + o_lW1);
    u16* b1c    = (u16*)(ws + o_b1);
    u16* W2c    = (u16*)(ws + o_W2);
    u16* lW2c   = (u16*)(ws + o_lW2);
    u16* b2c    = (u16*)(ws + o_b2);
    u16* h      = (u16*)(ws + o_h);
    int* offs   = (int*)(ws + o_offs);
    int* gcnt   = (int*)(ws + o_gcnt);
    int* bstart = (int*)(ws + o_bst);
    int* bcur   = (int*)(ws + o_bcur);
    u32* ebuf   = (u32*)(ws + o_ebuf);
    int* rowidx = (int*)(ws + o_ridx);

    dim3 blk(256, 1, 1);
    int mb    = (N + BM - 1) / BM;            // 1563 blocks
    int nblkE = (E + CH - 1) / CH;
    auto cdiv = [](long long n) { return (u32)((n + 255) / 256); };

    detect_dtype<<<dim3(1), blk, 0, stream>>>((const u16*)x_in, flag, gcnt, nbuck);
    long long tot = ND + RDD + DDl + D + RDD + DDl + D;
    to_bf16_all<<<dim3(cdiv(tot)), blk, 0, stream>>>(
        x_in, W1_in, lW1_in, b1_in, W2_in, lW2_in, b2_in,
        x_c, W1c, lW1c, b1c, W2c, lW2c, b2c,
        ND, RDD, DDl, (long long)D, RDD, DDl, (long long)D, flag);

    // CSR build (bucketed counting sort)
    csr_count<<<dim3(nblkE), blk, 0, stream>>>(dst, gcnt, E, nbuck);
    csr_scan<<<dim3(1), blk, 0, stream>>>(gcnt, bstart, bcur, nbuck, N, E, offs);
    csr_part<<<dim3(nblkE), blk, 0, stream>>>(src, dst, et, bcur, ebuf, E, N, nbuck);
    csr_emit<<<dim3(nbuck), blk, 0, stream>>>(ebuf, bstart, offs, rowidx, N);

    // layer 1: fused gather + deep GEMM (K=(R+1)*128), bias+relu
    rel_layer_fused<<<dim3(mb), dim3(128), 0, stream>>>(
        x_c, (const u16*)x_in, offs, rowidx,
        W1c, (const u16*)W1_in, lW1c, (const u16*)lW1_in,
        b1c, (const u16*)b1_in, flag, N, R, 0, h);

    // layer 2: fused gather + deep GEMM, bias + row-L2-normalize
    rel_layer_fused<<<dim3(mb), dim3(128), 0, stream>>>(
        h, h, offs, rowidx,
        W2c, (const u16*)W2_in, lW2c, (const u16*)lW2_in,
        b2c, (const u16*)b2_in, flag, N, R, 1, d_out);
}

// Round 3
// 438.641 us; speedup vs baseline: 1.4323x; 1.4323x over previous
//
#include <hip/hip_runtime.h>
#include <hip/hip_bf16.h>

#define D 128
#define CH 4096   // edges per block in CSR partition passes
#define BM 16     // dst rows per fused block (4 waves x 4 rows)

typedef unsigned int u32;
typedef unsigned short u16;
typedef __attribute__((ext_vector_type(8))) short s16x8;
typedef __attribute__((ext_vector_type(4))) float f32x4;
typedef __attribute__((ext_vector_type(2))) float f32x2;

__device__ __forceinline__ float bf2f(u16 u) {
    union { u32 u; float f; } v; v.u = ((u32)u) << 16; return v.f;
}
__device__ __forceinline__ u16 f2bf(float f) {
    union { float f; u32 u; } v; v.f = f;
    return (u16)((v.u + 0x7fffu + ((v.u >> 16) & 1u)) >> 16);
}
__device__ __forceinline__ u32 pack_bf2(float a, float b) {
    __hip_bfloat162 t = __float22bfloat162_rn(make_float2(a, b));
    union { __hip_bfloat162 t; u32 u; } v; v.t = t; return v.u;
}
__device__ __forceinline__ void unpack2(u32 u, float& lo, float& hi) {
    union { u32 u; float f; } a, b;
    a.u = u << 16; b.u = u & 0xffff0000u;
    lo = a.f; hi = b.f;
}

// ---- dtype detector (also zeroes gcnt for the CSR build) ----
__global__ void detect_dtype(const u16* __restrict__ x, int* __restrict__ flag,
                             int* __restrict__ gcnt, int nbuck) {
    __shared__ int cnt;
    if (threadIdx.x == 0) cnt = 0;
    __syncthreads();
    if ((int)threadIdx.x < nbuck) gcnt[threadIdx.x] = 0;
    u16 u = x[2 * threadIdx.x];
    int e = (u >> 7) & 0xFF;
    if (e >= 96 && e <= 150) atomicAdd(&cnt, 1);
    __syncthreads();
    if (threadIdx.x == 0) *flag = (cnt >= 128) ? 0 : 1;
}

// ---- canonicalize (body only runs when inputs are fp32) ----
__global__ __launch_bounds__(256)
void to_bf16_all(const void* __restrict__ s0, const void* __restrict__ s1,
                 const void* __restrict__ s2, const void* __restrict__ s3,
                 const void* __restrict__ s4, const void* __restrict__ s5,
                 const void* __restrict__ s6,
                 u16* __restrict__ d0, u16* __restrict__ d1, u16* __restrict__ d2,
                 u16* __restrict__ d3, u16* __restrict__ d4, u16* __restrict__ d5,
                 u16* __restrict__ d6,
                 long long n0, long long n1, long long n2, long long n3,
                 long long n4, long long n5, long long n6,
                 const int* __restrict__ flag)
{
    if (*flag == 0) return;
    long long i = (long long)blockIdx.x * 256 + threadIdx.x;
    const void* s; u16* d; long long off;
    if      (i < n0)                   { s = s0; d = d0; off = i; }
    else if (i < n0+n1)                { s = s1; d = d1; off = i-n0; }
    else if (i < n0+n1+n2)             { s = s2; d = d2; off = i-n0-n1; }
    else if (i < n0+n1+n2+n3)          { s = s3; d = d3; off = i-n0-n1-n2; }
    else if (i < n0+n1+n2+n3+n4)       { s = s4; d = d4; off = i-n0-n1-n2-n3; }
    else if (i < n0+n1+n2+n3+n4+n5)    { s = s5; d = d5; off = i-n0-n1-n2-n3-n4; }
    else if (i < n0+n1+n2+n3+n4+n5+n6) { s = s6; d = d6; off = i-n0-n1-n2-n3-n4-n5; }
    else return;
    d[off] = f2bf(((const float*)s)[off]);
}

// ==== bucketed CSR build: bucket = dst>>8 (needs N<=65536, src<2^16, et<8) ====
__global__ __launch_bounds__(256)
void csr_count(const int* __restrict__ dst, int* __restrict__ gcnt, int E, int nbuck) {
    __shared__ int scnt[256];
    int tid = threadIdx.x;
    scnt[tid] = 0;
    __syncthreads();
    int base = blockIdx.x * CH;
#pragma unroll
    for (int it = 0; it < CH / 256; ++it) {
        int e = base + it * 256 + tid;
        if (e < E) atomicAdd(&scnt[dst[e] >> 8], 1);
    }
    __syncthreads();
    if (tid < nbuck && scnt[tid] > 0) atomicAdd(&gcnt[tid], scnt[tid]);
}

__global__ __launch_bounds__(256)
void csr_scan(const int* __restrict__ gcnt, int* __restrict__ bstart, int* __restrict__ bcur,
              int nbuck, int N_, int E_, int* __restrict__ offs) {
    __shared__ int wpart[4];
    int tid = threadIdx.x, lane = tid & 63, wid = tid >> 6;
    int v = (tid < nbuck) ? gcnt[tid] : 0;
    int s = v;
#pragma unroll
    for (int off = 1; off < 64; off <<= 1) {
        int t = __shfl_up(s, off, 64);
        if (lane >= off) s += t;
    }
    if (lane == 63) wpart[wid] = s;
    __syncthreads();
    int add = 0;
    for (int w = 0; w < wid; ++w) add += wpart[w];
    int excl = add + s - v;
    if (tid <= nbuck) bstart[tid] = excl;
    if (tid < nbuck)  bcur[tid]  = excl;
    if (tid == 0) offs[N_] = E_;
}

// partition edges into bucket-contiguous ebuf; rec = (dst&255)<<24 | (et<<16) | src
__global__ __launch_bounds__(256)
void csr_part(const int* __restrict__ src, const int* __restrict__ dst,
              const int* __restrict__ et, int* __restrict__ bcur,
              u32* __restrict__ ebuf, int E, int N, int nbuck) {
    __shared__ int scnt[256], sbase[256];
    int tid = threadIdx.x;
    scnt[tid] = 0;
    __syncthreads();
    int base = blockIdx.x * CH;
#pragma unroll
    for (int it = 0; it < CH / 256; ++it) {
        int e = base + it * 256 + tid;
        if (e < E) atomicAdd(&scnt[dst[e] >> 8], 1);
    }
    __syncthreads();
    if (tid < nbuck) {
        int c = scnt[tid];
        sbase[tid] = c ? atomicAdd(&bcur[tid], c) : 0;
    }
    __syncthreads();
    scnt[tid] = 0;
    __syncthreads();
#pragma unroll
    for (int it = 0; it < CH / 256; ++it) {
        int e = base + it * 256 + tid;
        if (e >= E) continue;
        int d = dst[e];
        int b = d >> 8;
        int p = sbase[b] + atomicAdd(&scnt[b], 1);
        ebuf[p] = ((u32)(d & 255) << 24) | ((u32)et[e] << 16) | (u32)src[e];
    }
}

// one block per bucket: 2048-bin (dstlo*8 + et) counting sort -> offs + rowidx
// output edges are sorted by (dst, et): the fused gather needs no per-edge switch
__global__ __launch_bounds__(256)
void csr_emit(const u32* __restrict__ ebuf, const int* __restrict__ bstart,
              int* __restrict__ offs, int* __restrict__ rowidx, int N) {
    __shared__ int hist[2048], excl[2048], cur[2048];
    __shared__ int wpart[4];
    int b = blockIdx.x, tid = threadIdx.x;
    int lo = bstart[b], hi = bstart[b + 1];
    for (int i = tid; i < 2048; i += 256) { hist[i] = 0; cur[i] = 0; }
    __syncthreads();
    for (int i = lo + tid; i < hi; i += 256) {
        u32 rec = ebuf[i];
        int key = (int)((rec >> 24) << 3) | (int)((rec >> 16) & 7u);
        atomicAdd(&hist[key], 1);
    }
    __syncthreads();
    int loc[8]; int tsum = 0;
#pragma unroll
    for (int k = 0; k < 8; ++k) { loc[k] = tsum; tsum += hist[tid * 8 + k]; }
    int lane = tid & 63, wid = tid >> 6;
    int s = tsum;
#pragma unroll
    for (int off = 1; off < 64; off <<= 1) {
        int t = __shfl_up(s, off, 64);
        if (lane >= off) s += t;
    }
    if (lane == 63) wpart[wid] = s;
    __syncthreads();
    int add = 0;
    for (int w = 0; w < wid; ++w) add += wpart[w];
    int tex = add + s - tsum;
#pragma unroll
    for (int k = 0; k < 8; ++k) excl[tid * 8 + k] = tex + loc[k];
    int node = (b << 8) + tid;
    if (node < N) offs[node] = lo + tex;
    __syncthreads();
    for (int i = lo + tid; i < hi; i += 256) {
        u32 rec = ebuf[i];
        int key = (int)((rec >> 24) << 3) | (int)((rec >> 16) & 7u);
        int p = lo + excl[key] + atomicAdd(&cur[key], 1);
        rowidx[p] = (int)(rec & 0xFFFFFFu);
    }
}

// ---- build W fragments: wt[layer][plane 0..8][wv][ks][h][lane][8] bf16 ----
// fragment element = W[k = ks*32 + (lane>>4)*8 + j][col = wv*32 + 2*(lane&15) + h]
// plane 8 = loopW. One coalesced dwordx4 per (ks,h) in the GEMM.
__global__ __launch_bounds__(256)
void build_wt(const u16* __restrict__ W1c, const u16* __restrict__ W1o,
              const u16* __restrict__ lW1c, const u16* __restrict__ lW1o,
              const u16* __restrict__ W2c, const u16* __restrict__ W2o,
              const u16* __restrict__ lW2c, const u16* __restrict__ lW2o,
              const int* __restrict__ flag, int R_, u16* __restrict__ wt)
{
    __shared__ u32 st[8192];
    bool f = (*flag != 0);
    int m = blockIdx.x;          // 0..17: layer = m/9, plane c = m%9
    int layer = m / 9, c = m % 9;
    const u16* src;
    if (layer == 0) src = (c < R_) ? ((f ? W1c : W1o) + (size_t)c * D * D) : (f ? lW1c : lW1o);
    else            src = (c < R_) ? ((f ? W2c : W2o) + (size_t)c * D * D) : (f ? lW2c : lW2o);
    int tid = threadIdx.x;
    const u32* s32 = (const u32*)src;
    for (int i = tid; i < 8192; i += 256) st[i] = s32[i];
    __syncthreads();
    const u16* st16 = (const u16*)st;
    u16* dstp = wt + (size_t)m * 16384;
    for (int i = tid; i < 16384; i += 256) {
        int wvv = i >> 12;
        int ks  = (i >> 10) & 3;
        int h   = (i >> 9) & 1;
        int ln  = (i >> 3) & 63;
        int j   = i & 7;
        int k   = ks * 32 + (ln >> 4) * 8 + j;
        int col = wvv * 32 + 2 * (ln & 15) + h;
        dstp[i] = st16[k * 128 + col];
    }
}

// ==== fused layer, BM=16 rows per block, 4 waves (each owns 4 rows) ====
// Phase 1: gather per-(node,rel) sums from x (LLC-resident) directly into bf16 LDS
//   planes [rel][row][128] (XOR chunk swizzle). Edges are (dst,et)-sorted, so the
//   scan is linear with flush-on-boundary (no per-edge switch). Self plane via
//   global_load_lds with pre-swizzled source.
// Phase 2: C[16x128] = sum_c planes[c] @ W_c (K=(R+1)*128) from pre-fragmented wt.
// mode 0: +bias, relu, bf16. mode 1: +bias, row-L2-normalize, f32/bf16 out.
__global__ __launch_bounds__(256, 4)
void rel_layer_fused(const u16* __restrict__ xc, const u16* __restrict__ xo,
                     const int* __restrict__ offs, const int* __restrict__ rowidx,
                     const u16* __restrict__ wt,
                     const u16* __restrict__ bc, const u16* __restrict__ bo,
                     const int* __restrict__ flag,
                     int M, int R_, int mode, void* __restrict__ out)
{
    __shared__ u16 As[9 * BM * D];   // 36864 B -> 4 blocks/CU (16 waves/CU)
    const bool f = (*flag != 0);
    const u16* X    = f ? xc : xo;
    const u16* bias = f ? bc : bo;

    const int row0 = blockIdx.x * BM;
    const int tid  = threadIdx.x;
    const int lane = tid & 63;
    const int wv   = tid >> 6;        // 0..3
    const int quad = lane >> 4;
    const int l16  = lane & 15;

    // ---- stage self plane (plane 8): one global_load_lds per wave ----
    {
        auto* lds0 = (__attribute__((address_space(3))) char*)As;
        int rl = wv * 4 + quad;
        int rg = row0 + rl; if (rg >= M) rg = M - 1;
        int cg = l16 ^ rl;            // pre-swizzled source chunk
        const u16* gp = X + (size_t)rg * D + cg * 8;
        __builtin_amdgcn_global_load_lds(
            (const __attribute__((address_space(1))) void*)gp,
            (__attribute__((address_space(3))) void*)(lds0 + 8 * BM * 256 + wv * 1024),
            16, 0, 0);
    }

    // ---- zero relation planes for this wave's rows ----
    {
        u32* pz = (u32*)As;
        int rbase = wv * 4;
#pragma unroll
        for (int pl = 0; pl < 8; ++pl)
#pragma unroll
            for (int rr = 0; rr < 4; ++rr)
                pz[(pl * BM + rbase + rr) * 64 + lane] = 0;
    }

    // ---- gather phase ----
    {
        const u32* X32 = (const u32*)X;
        u32* plane = (u32*)As;
        int v0 = row0 + wv * 4;
        int idx = v0 + lane; if (idx > M) idx = M;
        int offv = offs[idx];          // lanes 0..4 hold this wave's row offsets
        int jbase = __builtin_amdgcn_readlane(offv, 0);
        int jend  = __builtin_amdgcn_readlane(offv, 4);
        int nE = jend - jbase;
        if (nE > 0 && nE <= 128) {
            int vrow = rowidx[(jbase + lane < jend) ? jbase + lane : jend - 1];
            int vrow2 = 0;
            if (nE > 64) vrow2 = rowidx[(jbase + 64 + lane < jend) ? jbase + 64 + lane : jend - 1];
            int rowptr = 0;
            int rnext = __builtin_amdgcn_readlane(offv, 1);
            int rl = wv * 4;
            int vsw = (((lane >> 2) ^ rl) << 2) | (lane & 3);
            int rcur = -1;
            float a0 = 0.f, a1 = 0.f;
            int j = jbase;
            while (j < jend) {
                int nb = jend - j; if (nb > 8) nb = 8;
                int rec[8]; u32 g[8];
#pragma unroll
                for (int k = 0; k < 8; ++k) {
                    if (k < nb) {
                        int kk = j - jbase + k;
                        rec[k] = (kk < 64) ? __builtin_amdgcn_readlane(vrow, kk)
                                           : __builtin_amdgcn_readlane(vrow2, kk - 64);
                    }
                }
#pragma unroll
                for (int k = 0; k < 8; ++k)
                    if (k < nb) g[k] = X32[(size_t)(rec[k] & 0xffff) * 64 + lane];
#pragma unroll
                for (int k = 0; k < 8; ++k) {
                    if (k < nb) {
                        int jj = j + k;
                        while (jj >= rnext) {     // advance to the row owning edge jj
                            if (rcur >= 0) {
                                plane[(rcur * BM + rl) * 64 + vsw] = pack_bf2(a0, a1);
                                rcur = -1; a0 = 0.f; a1 = 0.f;
                            }
                            rowptr++;
                            rl = wv * 4 + rowptr;
                            vsw = (((lane >> 2) ^ rl) << 2) | (lane & 3);
                            rnext = __builtin_amdgcn_readlane(offv, rowptr + 1);
                        }
                        int et = rec[k] >> 16;
                        if (et != rcur) {         // relation boundary: flush
                            if (rcur >= 0) plane[(rcur * BM + rl) * 64 + vsw] = pack_bf2(a0, a1);
                            rcur = et; a0 = 0.f; a1 = 0.f;
                        }
                        float lo_, hi_;
                        unpack2(g[k], lo_, hi_);
                        a0 += lo_; a1 += hi_;
                    }
                }
                j += nb;
            }
            if (rcur >= 0) plane[(rcur * BM + rl) * 64 + vsw] = pack_bf2(a0, a1);
        } else if (nE > 128) {
            // very-high-degree fallback: serial per row (cold path)
            for (int rr = 0; rr < 4; ++rr) {
                int j0 = __builtin_amdgcn_readlane(offv, rr);
                int j1 = __builtin_amdgcn_readlane(offv, rr + 1);
                int rl = wv * 4 + rr;
                int vsw = (((lane >> 2) ^ rl) << 2) | (lane & 3);
                int rcur = -1; float a0 = 0.f, a1 = 0.f;
                for (int j = j0; j < j1; ++j) {
                    u32 rec = (u32)rowidx[j];
                    int et = (int)(rec >> 16);
                    if (et != rcur) {
                        if (rcur >= 0) plane[(rcur * BM + rl) * 64 + vsw] = pack_bf2(a0, a1);
                        rcur = et; a0 = 0.f; a1 = 0.f;
                    }
                    float lo_, hi_;
                    unpack2(X32[(size_t)(rec & 0xffff) * 64 + lane], lo_, hi_);
                    a0 += lo_; a1 += hi_;
                }
                if (rcur >= 0) plane[(rcur * BM + rl) * 64 + vsw] = pack_bf2(a0, a1);
            }
        }
    }

    __syncthreads();   // drains global_load_lds + LDS writes

    // ---- MFMA phase: wave wv computes rows 0..15 x cols [wv*32, wv*32+32) ----
    f32x4 acc[2];
    acc[0] = (f32x4)0.f; acc[1] = (f32x4)0.f;
    for (int c = 0; c <= R_; ++c) {
        int cidx = (c < R_) ? c : 8;
        const u16* Bt = wt + (size_t)cidx * 16384 + (size_t)wv * 4096 + lane * 8;
        s16x8 bfr[4][2];
#pragma unroll
        for (int ks = 0; ks < 4; ++ks)
#pragma unroll
            for (int h = 0; h < 2; ++h)
                bfr[ks][h] = *(const s16x8*)(Bt + (ks * 2 + h) * 512);
#pragma unroll
        for (int ks = 0; ks < 4; ++ks) {
            int chp = (ks * 4 + quad) ^ l16;
            s16x8 a = *(const s16x8*)(As + (cidx * BM + l16) * D + chp * 8);
            acc[0] = __builtin_amdgcn_mfma_f32_16x16x32_bf16(a, bfr[ks][0], acc[0], 0, 0, 0);
            acc[1] = __builtin_amdgcn_mfma_f32_16x16x32_bf16(a, bfr[ks][1], acc[1], 0, 0, 0);
        }
    }

    const int cp = wv * 16 + l16;      // colpair 0..63
    const float b0 = bf2f(bias[2 * cp]);
    const float b1 = bf2f(bias[2 * cp + 1]);

    if (mode == 0) {
        u32* o = (u32*)out;
#pragma unroll
        for (int i = 0; i < 4; ++i) {
            int r = row0 + quad * 4 + i;
            if (r >= M) continue;
            o[(size_t)r * 64 + cp] = pack_bf2(fmaxf(acc[0][i] + b0, 0.f),
                                              fmaxf(acc[1][i] + b1, 0.f));
        }
    } else {
        __syncthreads();               // planes no longer needed: reuse as scratch
        float* fs = (float*)As;        // fs[row*4 + wv]
        float pr[4];
#pragma unroll
        for (int i = 0; i < 4; ++i) {
            float a0 = acc[0][i] + b0;
            float a1 = acc[1][i] + b1;
            acc[0][i] = a0; acc[1][i] = a1;
            float p = a0 * a0 + a1 * a1;
            p += __shfl_xor(p, 1, 64);
            p += __shfl_xor(p, 2, 64);
            p += __shfl_xor(p, 4, 64);
            p += __shfl_xor(p, 8, 64);
            pr[i] = p;                 // this wave's 32-col partial for row quad*4+i
        }
        if (l16 == 0) {
#pragma unroll
            for (int i = 0; i < 4; ++i) fs[(quad * 4 + i) * 4 + wv] = pr[i];
        }
        __syncthreads();
#pragma unroll
        for (int i = 0; i < 4; ++i) {
            int rl = quad * 4 + i;
            int r = row0 + rl;
            if (r >= M) continue;
            float ssum = fs[rl * 4] + fs[rl * 4 + 1] + fs[rl * 4 + 2] + fs[rl * 4 + 3];
            float sc = 1.f / fmaxf(sqrtf(ssum), 1e-12f);
            float a0 = acc[0][i] * sc, a1 = acc[1][i] * sc;
            if (f) {
                f32x2 w; w[0] = a0; w[1] = a1;
                ((f32x2*)out)[(size_t)r * 64 + cp] = w;
            } else {
                ((u32*)out)[(size_t)r * 64 + cp] = pack_bf2(a0, a1);
            }
        }
    }
}

static inline size_t align256(size_t x) { return (x + 255) & ~(size_t)255; }

extern "C" void kernel_launch(void* const* d_in, const int* in_sizes, int n_in,
                              void* d_out, int out_size, void* d_ws, size_t ws_size,
                              hipStream_t stream)
{
    const void* x_in   = d_in[0];
    const void* W1_in  = d_in[1];
    const void* lW1_in = d_in[2];
    const void* b1_in  = d_in[3];
    const void* W2_in  = d_in[4];
    const void* lW2_in = d_in[5];
    const void* b2_in  = d_in[6];
    const int* src = (const int*)d_in[7];
    const int* dst = (const int*)d_in[8];
    const int* et  = (const int*)d_in[9];

    const int N = in_sizes[0] / D;            // 50000
    const int E = in_sizes[7];                // 800000
    const int R = in_sizes[1] / (D * D);      // 8
    const int nbuck = (N + 255) >> 8;         // 196

    const long long ND  = (long long)N * D;
    const long long RDD = (long long)R * D * D;
    const long long DDl = (long long)D * D;

    size_t off = 0;
    auto alloc = [&](size_t bytes) { size_t o = off; off = align256(off + bytes); return o; };
    size_t o_flag = alloc(256);
    size_t o_xc   = alloc((size_t)ND * 2);
    size_t o_W1   = alloc((size_t)RDD * 2);
    size_t o_lW1  = alloc((size_t)DDl * 2);
    size_t o_b1   = alloc((size_t)D * 2);
    size_t o_W2   = alloc((size_t)RDD * 2);
    size_t o_lW2  = alloc((size_t)DDl * 2);
    size_t o_b2   = alloc((size_t)D * 2);
    size_t o_h    = alloc((size_t)ND * 2);
    size_t o_offs = alloc((size_t)(N + 1) * 4);
    size_t o_gcnt = alloc(1024);
    size_t o_bst  = alloc(1040 * 4);
    size_t o_bcur = alloc(1024);
    size_t o_ebuf = alloc((size_t)E * 4);
    size_t o_ridx = alloc((size_t)E * 4);
    size_t o_wt   = alloc((size_t)2 * 9 * D * D * 2);  // fragment-ordered weights
    (void)ws_size;

    char* ws = (char*)d_ws;
    int* flag   = (int*)(ws + o_flag);
    u16* x_c    = (u16*)(ws + o_xc);
    u16* W1c    = (u16*)(ws + o_W1);
    u16* lW1c   = (u16*)(ws + o_lW1);
    u16* b1c    = (u16*)(ws + o_b1);
    u16* W2c    = (u16*)(ws + o_W2);
    u16* lW2c   = (u16*)(ws + o_lW2);
    u16* b2c    = (u16*)(ws + o_b2);
    u16* h      = (u16*)(ws + o_h);
    int* offs   = (int*)(ws + o_offs);
    int* gcnt   = (int*)(ws + o_gcnt);
    int* bstart = (int*)(ws + o_bst);
    int* bcur   = (int*)(ws + o_bcur);
    u32* ebuf   = (u32*)(ws + o_ebuf);
    int* rowidx = (int*)(ws + o_ridx);
    u16* wt     = (u16*)(ws + o_wt);

    dim3 blk(256, 1, 1);
    int mb    = (N + BM - 1) / BM;            // 3125 blocks
    int nblkE = (E + CH - 1) / CH;
    auto cdiv = [](long long n) { return (u32)((n + 255) / 256); };

    detect_dtype<<<dim3(1), blk, 0, stream>>>((const u16*)x_in, flag, gcnt, nbuck);
    long long tot = ND + RDD + DDl + D + RDD + DDl + D;
    to_bf16_all<<<dim3(cdiv(tot)), blk, 0, stream>>>(
        x_in, W1_in, lW1_in, b1_in, W2_in, lW2_in, b2_in,
        x_c, W1c, lW1c, b1c, W2c, lW2c, b2c,
        ND, RDD, DDl, (long long)D, RDD, DDl, (long long)D, flag);

    build_wt<<<dim3(18), blk, 0, stream>>>(
        W1c, (const u16*)W1_in, lW1c, (const u16*)lW1_in,
        W2c, (const u16*)W2_in, lW2c, (const u16*)lW2_in, flag, R, wt);

    // CSR build: (dst, et)-sorted edge lists
    csr_count<<<dim3(nblkE), blk, 0, stream>>>(dst, gcnt, E, nbuck);
    csr_scan<<<dim3(1), blk, 0, stream>>>(gcnt, bstart, bcur, nbuck, N, E, offs);
    csr_part<<<dim3(nblkE), blk, 0, stream>>>(src, dst, et, bcur, ebuf, E, N, nbuck);
    csr_emit<<<dim3(nbuck), blk, 0, stream>>>(ebuf, bstart, offs, rowidx, N);

    // layer 1: fused gather + deep GEMM (K=(R+1)*128), bias+relu
    rel_layer_fused<<<dim3(mb), blk, 0, stream>>>(
        x_c, (const u16*)x_in, offs, rowidx, wt,
        b1c, (const u16*)b1_in, flag, N, R, 0, h);

    // layer 2: fused gather + deep GEMM, bias + row-L2-normalize
    rel_layer_fused<<<dim3(mb), blk, 0, stream>>>(
        h, h, offs, rowidx, wt + (size_t)9 * D * D,
        b2c, (const u16*)b2_in, flag, N, R, 1, d_out);
}

// Round 4
// 304.703 us; speedup vs baseline: 2.0618x; 1.4396x over previous
//
#include <hip/hip_runtime.h>
#include <hip/hip_bf16.h>

#define D 128
#define CH 4096   // edges per block in CSR partition passes
#define BM 16     // dst rows per fused block (8 waves x 2 rows)

typedef unsigned int u32;
typedef unsigned short u16;
typedef __attribute__((ext_vector_type(8))) short s16x8;
typedef __attribute__((ext_vector_type(4))) float f32x4;
typedef __attribute__((ext_vector_type(2))) float f32x2;

__device__ __forceinline__ float bf2f(u16 u) {
    union { u32 u; float f; } v; v.u = ((u32)u) << 16; return v.f;
}
__device__ __forceinline__ u16 f2bf(float f) {
    union { float f; u32 u; } v; v.f = f;
    return (u16)((v.u + 0x7fffu + ((v.u >> 16) & 1u)) >> 16);
}
__device__ __forceinline__ u32 pack_bf2(float a, float b) {
    __hip_bfloat162 t = __float22bfloat162_rn(make_float2(a, b));
    union { __hip_bfloat162 t; u32 u; } v; v.t = t; return v.u;
}
__device__ __forceinline__ void unpack2(u32 u, float& lo, float& hi) {
    union { u32 u; float f; } a, b;
    a.u = u << 16; b.u = u & 0xffff0000u;
    lo = a.f; hi = b.f;
}

// ---- dtype detector (also zeroes gcnt for the CSR build) ----
__global__ void detect_dtype(const u16* __restrict__ x, int* __restrict__ flag,
                             int* __restrict__ gcnt, int nbuck) {
    __shared__ int cnt;
    if (threadIdx.x == 0) cnt = 0;
    __syncthreads();
    if ((int)threadIdx.x < nbuck) gcnt[threadIdx.x] = 0;
    u16 u = x[2 * threadIdx.x];
    int e = (u >> 7) & 0xFF;
    if (e >= 96 && e <= 150) atomicAdd(&cnt, 1);
    __syncthreads();
    if (threadIdx.x == 0) *flag = (cnt >= 128) ? 0 : 1;
}

// ---- canonicalize (body only runs when inputs are fp32) ----
__global__ __launch_bounds__(256)
void to_bf16_all(const void* __restrict__ s0, const void* __restrict__ s1,
                 const void* __restrict__ s2, const void* __restrict__ s3,
                 const void* __restrict__ s4, const void* __restrict__ s5,
                 const void* __restrict__ s6,
                 u16* __restrict__ d0, u16* __restrict__ d1, u16* __restrict__ d2,
                 u16* __restrict__ d3, u16* __restrict__ d4, u16* __restrict__ d5,
                 u16* __restrict__ d6,
                 long long n0, long long n1, long long n2, long long n3,
                 long long n4, long long n5, long long n6,
                 const int* __restrict__ flag)
{
    if (*flag == 0) return;
    long long i = (long long)blockIdx.x * 256 + threadIdx.x;
    const void* s; u16* d; long long off;
    if      (i < n0)                   { s = s0; d = d0; off = i; }
    else if (i < n0+n1)                { s = s1; d = d1; off = i-n0; }
    else if (i < n0+n1+n2)             { s = s2; d = d2; off = i-n0-n1; }
    else if (i < n0+n1+n2+n3)          { s = s3; d = d3; off = i-n0-n1-n2; }
    else if (i < n0+n1+n2+n3+n4)       { s = s4; d = d4; off = i-n0-n1-n2-n3; }
    else if (i < n0+n1+n2+n3+n4+n5)    { s = s5; d = d5; off = i-n0-n1-n2-n3-n4; }
    else if (i < n0+n1+n2+n3+n4+n5+n6) { s = s6; d = d6; off = i-n0-n1-n2-n3-n4-n5; }
    else return;
    d[off] = f2bf(((const float*)s)[off]);
}

// ==== bucketed CSR build: bucket = dst>>8 (needs N<=65536, src<2^16, et<8) ====
__global__ __launch_bounds__(256)
void csr_count(const int* __restrict__ dst, int* __restrict__ gcnt, int E, int nbuck) {
    __shared__ int scnt[256];
    int tid = threadIdx.x;
    scnt[tid] = 0;
    __syncthreads();
    int base = blockIdx.x * CH;
#pragma unroll
    for (int it = 0; it < CH / 256; ++it) {
        int e = base + it * 256 + tid;
        if (e < E) atomicAdd(&scnt[dst[e] >> 8], 1);
    }
    __syncthreads();
    if (tid < nbuck && scnt[tid] > 0) atomicAdd(&gcnt[tid], scnt[tid]);
}

__global__ __launch_bounds__(256)
void csr_scan(const int* __restrict__ gcnt, int* __restrict__ bstart, int* __restrict__ bcur,
              int nbuck, int N_, int E_, int* __restrict__ offs) {
    __shared__ int wpart[4];
    int tid = threadIdx.x, lane = tid & 63, wid = tid >> 6;
    int v = (tid < nbuck) ? gcnt[tid] : 0;
    int s = v;
#pragma unroll
    for (int off = 1; off < 64; off <<= 1) {
        int t = __shfl_up(s, off, 64);
        if (lane >= off) s += t;
    }
    if (lane == 63) wpart[wid] = s;
    __syncthreads();
    int add = 0;
    for (int w = 0; w < wid; ++w) add += wpart[w];
    int excl = add + s - v;
    if (tid <= nbuck) bstart[tid] = excl;
    if (tid < nbuck)  bcur[tid]  = excl;
    if (tid == 0) offs[N_] = E_;
}

// partition edges into bucket-contiguous ebuf; rec = (dst&255)<<24 | (et<<16) | src
__global__ __launch_bounds__(256)
void csr_part(const int* __restrict__ src, const int* __restrict__ dst,
              const int* __restrict__ et, int* __restrict__ bcur,
              u32* __restrict__ ebuf, int E, int N, int nbuck) {
    __shared__ int scnt[256], sbase[256];
    int tid = threadIdx.x;
    scnt[tid] = 0;
    __syncthreads();
    int base = blockIdx.x * CH;
#pragma unroll
    for (int it = 0; it < CH / 256; ++it) {
        int e = base + it * 256 + tid;
        if (e < E) atomicAdd(&scnt[dst[e] >> 8], 1);
    }
    __syncthreads();
    if (tid < nbuck) {
        int c = scnt[tid];
        sbase[tid] = c ? atomicAdd(&bcur[tid], c) : 0;
    }
    __syncthreads();
    scnt[tid] = 0;
    __syncthreads();
#pragma unroll
    for (int it = 0; it < CH / 256; ++it) {
        int e = base + it * 256 + tid;
        if (e >= E) continue;
        int d = dst[e];
        int b = d >> 8;
        int p = sbase[b] + atomicAdd(&scnt[b], 1);
        ebuf[p] = ((u32)(d & 255) << 24) | ((u32)et[e] << 16) | (u32)src[e];
    }
}

// one block per bucket: 2048-bin (dstlo*8 + et) counting sort -> offs + rowidx
// output edges are sorted by (dst, et): the fused gather needs no per-edge switch
__global__ __launch_bounds__(256)
void csr_emit(const u32* __restrict__ ebuf, const int* __restrict__ bstart,
              int* __restrict__ offs, int* __restrict__ rowidx, int N) {
    __shared__ int hist[2048], excl[2048], cur[2048];
    __shared__ int wpart[4];
    int b = blockIdx.x, tid = threadIdx.x;
    int lo = bstart[b], hi = bstart[b + 1];
    for (int i = tid; i < 2048; i += 256) { hist[i] = 0; cur[i] = 0; }
    __syncthreads();
    for (int i = lo + tid; i < hi; i += 256) {
        u32 rec = ebuf[i];
        int key = (int)((rec >> 24) << 3) | (int)((rec >> 16) & 7u);
        atomicAdd(&hist[key], 1);
    }
    __syncthreads();
    int loc[8]; int tsum = 0;
#pragma unroll
    for (int k = 0; k < 8; ++k) { loc[k] = tsum; tsum += hist[tid * 8 + k]; }
    int lane = tid & 63, wid = tid >> 6;
    int s = tsum;
#pragma unroll
    for (int off = 1; off < 64; off <<= 1) {
        int t = __shfl_up(s, off, 64);
        if (lane >= off) s += t;
    }
    if (lane == 63) wpart[wid] = s;
    __syncthreads();
    int add = 0;
    for (int w = 0; w < wid; ++w) add += wpart[w];
    int tex = add + s - tsum;
#pragma unroll
    for (int k = 0; k < 8; ++k) excl[tid * 8 + k] = tex + loc[k];
    int node = (b << 8) + tid;
    if (node < N) offs[node] = lo + tex;
    __syncthreads();
    for (int i = lo + tid; i < hi; i += 256) {
        u32 rec = ebuf[i];
        int key = (int)((rec >> 24) << 3) | (int)((rec >> 16) & 7u);
        int p = lo + excl[key] + atomicAdd(&cur[key], 1);
        rowidx[p] = (int)(rec & 0xFFFFFFu);
    }
}

// ---- build W fragments: wt[layer][plane 0..8][wv:8][ks:4][lane:64][j:8] bf16 ----
// element = W[k = ks*32 + (lane>>4)*8 + j][col = wv*16 + (lane&15)] ; plane 8 = loopW
__global__ __launch_bounds__(256)
void build_wt(const u16* __restrict__ W1c, const u16* __restrict__ W1o,
              const u16* __restrict__ lW1c, const u16* __restrict__ lW1o,
              const u16* __restrict__ W2c, const u16* __restrict__ W2o,
              const u16* __restrict__ lW2c, const u16* __restrict__ lW2o,
              const int* __restrict__ flag, int R_, u16* __restrict__ wt)
{
    __shared__ u32 st[8192];
    bool f = (*flag != 0);
    int m = blockIdx.x;          // 0..17: layer = m/9, plane c = m%9
    int layer = m / 9, c = m % 9;
    const u16* src;
    if (layer == 0) src = (c < R_) ? ((f ? W1c : W1o) + (size_t)c * D * D) : (f ? lW1c : lW1o);
    else            src = (c < R_) ? ((f ? W2c : W2o) + (size_t)c * D * D) : (f ? lW2c : lW2o);
    int tid = threadIdx.x;
    const u32* s32 = (const u32*)src;
    for (int i = tid; i < 8192; i += 256) st[i] = s32[i];
    __syncthreads();
    const u16* st16 = (const u16*)st;
    u16* dstp = wt + (size_t)m * 16384;
    for (int i = tid; i < 16384; i += 256) {
        int wvv = i >> 11;
        int ks  = (i >> 9) & 3;
        int ln  = (i >> 3) & 63;
        int j   = i & 7;
        int k   = ks * 32 + (ln >> 4) * 8 + j;
        int col = wvv * 16 + (ln & 15);
        dstp[i] = st16[k * 128 + col];
    }
}

// gather one dst row's per-relation sums into bf16 LDS plane slots.
// window (up to 64 recs) preloaded in vrec; 16 gather loads in flight; per-edge
// work = unpack + 2 adds + wave-uniform et-compare (edges are (dst,et)-sorted).
__device__ __forceinline__ void gather_row(const u32* __restrict__ X32,
                                           const int* __restrict__ rowidx,
                                           u32* __restrict__ plane,
                                           int j0, int j1, int rl, int lane, int vrec)
{
    int deg = j1 - j0;
    if (deg <= 0) return;
    const int vsw = (((lane >> 2) ^ rl) << 2) | (lane & 3);
    int ecur = -1;
    float a0 = 0.f, a1 = 0.f;
    int base = j0;
    for (;;) {
        int wend = j1 - base; if (wend > 64) wend = 64;
        int pos = 0;
        while (pos < wend) {
            int nb = wend - pos; if (nb > 16) nb = 16;
            int srec[16]; u32 g[16];
#pragma unroll
            for (int k = 0; k < 16; ++k)
                if (k < nb) srec[k] = __builtin_amdgcn_readlane(vrec, pos + k);
#pragma unroll
            for (int k = 0; k < 16; ++k)
                if (k < nb) g[k] = X32[(size_t)(srec[k] & 0xffff) * 64 + lane];
#pragma unroll
            for (int k = 0; k < 16; ++k) {
                if (k < nb) {
                    int et = srec[k] >> 16;
                    if (et != ecur) {
                        if (ecur >= 0) plane[(ecur * BM + rl) * 64 + vsw] = pack_bf2(a0, a1);
                        ecur = et; a0 = 0.f; a1 = 0.f;
                    }
                    float lo_, hi_;
                    unpack2(g[k], lo_, hi_);
                    a0 += lo_; a1 += hi_;
                }
            }
            pos += nb;
        }
        base += wend;
        if (base >= j1) break;
        vrec = rowidx[(base + lane < j1) ? base + lane : j1 - 1];   // deg>64: rare
    }
    plane[(ecur * BM + rl) * 64 + vsw] = pack_bf2(a0, a1);
}

// ==== fused layer: BM=16 rows per block, 8 waves (each gathers 2 rows) ====
// Phase 1: per-(row,rel) sums gathered from x directly into bf16 LDS planes
//   [rel][row][128] (XOR chunk swizzle); self plane via global_load_lds.
// Phase 2: C[16x128] = sum_c planes[c] @ W_c (K=(R+1)*128); wave wv owns 16 cols.
// mode 0: +bias, relu, bf16. mode 1: +bias, row-L2-normalize, f32/bf16 out.
__global__ __launch_bounds__(512, 8)
void rel_layer_fused(const u16* __restrict__ xc, const u16* __restrict__ xo,
                     const int* __restrict__ offs, const int* __restrict__ rowidx,
                     const u16* __restrict__ wt,
                     const u16* __restrict__ bc, const u16* __restrict__ bo,
                     const int* __restrict__ flag,
                     int M, int R_, int mode, void* __restrict__ out)
{
    __shared__ u16 As[9 * BM * D];   // 36864 B -> 4 blocks/CU (32 waves/CU)
    const bool f = (*flag != 0);
    const u16* X    = f ? xc : xo;
    const u16* bias = f ? bc : bo;

    const int row0 = blockIdx.x * BM;
    const int tid  = threadIdx.x;
    const int lane = tid & 63;
    const int wv   = tid >> 6;        // 0..7
    const int quad = lane >> 4;
    const int l16  = lane & 15;

    // ---- stage self plane (plane 8): waves 0..3, 4 rows each ----
    if (wv < 4) {
        auto* lds0 = (__attribute__((address_space(3))) char*)As;
        int rl = wv * 4 + quad;
        int rg = row0 + rl; if (rg >= M) rg = M - 1;
        int cg = l16 ^ rl;            // pre-swizzled source chunk
        const u16* gp = X + (size_t)rg * D + cg * 8;
        __builtin_amdgcn_global_load_lds(
            (const __attribute__((address_space(1))) void*)gp,
            (__attribute__((address_space(3))) void*)(lds0 + 8 * BM * 256 + wv * 1024),
            16, 0, 0);
    }

    // ---- zero this wave's 2 rows across the 8 relation planes ----
    {
        u32* pz = (u32*)As;
        int rbase = wv * 2;
#pragma unroll
        for (int pl = 0; pl < 8; ++pl)
#pragma unroll
            for (int rr = 0; rr < 2; ++rr)
                pz[(pl * BM + rbase + rr) * 64 + lane] = 0;
    }

    // ---- gather phase: 2 rows per wave, both windows preloaded ----
    {
        const u32* X32 = (const u32*)X;
        u32* plane = (u32*)As;
        int rlA = wv * 2, rlB = rlA + 1;
        int rA = row0 + rlA, rB = row0 + rlB;
        int iA0 = rA < M ? rA : M, iA1 = rA + 1 < M ? rA + 1 : M;
        int iB0 = rB < M ? rB : M, iB1 = rB + 1 < M ? rB + 1 : M;
        int jA0 = offs[iA0], jA1 = offs[iA1];
        int jB0 = offs[iB0], jB1 = offs[iB1];
        int vrecA = 0, vrecB = 0;
        if (jA1 > jA0) vrecA = rowidx[(jA0 + lane < jA1) ? jA0 + lane : jA1 - 1];
        if (jB1 > jB0) vrecB = rowidx[(jB0 + lane < jB1) ? jB0 + lane : jB1 - 1];
        gather_row(X32, rowidx, plane, jA0, jA1, rlA, lane, vrecA);
        gather_row(X32, rowidx, plane, jB0, jB1, rlB, lane, vrecB);
    }

    __syncthreads();   // drains global_load_lds + LDS writes

    // ---- MFMA phase: wave wv computes rows 0..15 x cols [wv*16, wv*16+16) ----
    f32x4 acc = (f32x4)0.f;
    for (int c = 0; c <= R_; ++c) {
        int cidx = (c < R_) ? c : 8;
        const u16* Bt = wt + (size_t)cidx * 16384 + (size_t)wv * 2048 + lane * 8;
        s16x8 bfr[4];
#pragma unroll
        for (int ks = 0; ks < 4; ++ks)
            bfr[ks] = *(const s16x8*)(Bt + ks * 512);
#pragma unroll
        for (int ks = 0; ks < 4; ++ks) {
            int chp = (ks * 4 + quad) ^ l16;
            s16x8 a = *(const s16x8*)(As + (cidx * BM + l16) * D + chp * 8);
            acc = __builtin_amdgcn_mfma_f32_16x16x32_bf16(a, bfr[ks], acc, 0, 0, 0);
        }
    }

    const int col = wv * 16 + l16;     // 0..127
    const float b = bf2f(bias[col]);

    if (mode == 0) {
        u32* o = (u32*)out;
#pragma unroll
        for (int i = 0; i < 4; ++i) {
            int r = row0 + quad * 4 + i;
            float v = fmaxf(acc[i] + b, 0.f);
            float vp = __shfl_xor(v, 1, 64);
            if (!(l16 & 1) && r < M)
                o[(size_t)r * 64 + (col >> 1)] = pack_bf2(v, vp);
        }
    } else {
        float v[4];
        float pr[4];
#pragma unroll
        for (int i = 0; i < 4; ++i) {
            v[i] = acc[i] + b;
            float p = v[i] * v[i];
            p += __shfl_xor(p, 1, 64);
            p += __shfl_xor(p, 2, 64);
            p += __shfl_xor(p, 4, 64);
            p += __shfl_xor(p, 8, 64);
            pr[i] = p;                 // this wave's 16-col partial for row quad*4+i
        }
        __syncthreads();               // planes no longer needed: reuse as scratch
        float* fs = (float*)As;        // fs[row*8 + wv], scales at fs[128..143]
        if (l16 == 0) {
#pragma unroll
            for (int i = 0; i < 4; ++i) fs[(quad * 4 + i) * 8 + wv] = pr[i];
        }
        __syncthreads();
        if (tid < 16) {
            float s = 0.f;
#pragma unroll
            for (int w = 0; w < 8; ++w) s += fs[tid * 8 + w];
            fs[128 + tid] = 1.f / fmaxf(sqrtf(s), 1e-12f);
        }
        __syncthreads();
#pragma unroll
        for (int i = 0; i < 4; ++i) {
            int rl = quad * 4 + i;
            int r = row0 + rl;
            float sc = fs[128 + rl];
            float a0 = v[i] * sc;
            float ap = __shfl_xor(a0, 1, 64);
            if (!(l16 & 1) && r < M) {
                if (f) {
                    f32x2 w; w[0] = a0; w[1] = ap;
                    ((f32x2*)out)[(size_t)r * 64 + (col >> 1)] = w;
                } else {
                    ((u32*)out)[(size_t)r * 64 + (col >> 1)] = pack_bf2(a0, ap);
                }
            }
        }
    }
}

static inline size_t align256(size_t x) { return (x + 255) & ~(size_t)255; }

extern "C" void kernel_launch(void* const* d_in, const int* in_sizes, int n_in,
                              void* d_out, int out_size, void* d_ws, size_t ws_size,
                              hipStream_t stream)
{
    const void* x_in   = d_in[0];
    const void* W1_in  = d_in[1];
    const void* lW1_in = d_in[2];
    const void* b1_in  = d_in[3];
    const void* W2_in  = d_in[4];
    const void* lW2_in = d_in[5];
    const void* b2_in  = d_in[6];
    const int* src = (const int*)d_in[7];
    const int* dst = (const int*)d_in[8];
    const int* et  = (const int*)d_in[9];

    const int N = in_sizes[0] / D;            // 50000
    const int E = in_sizes[7];                // 800000
    const int R = in_sizes[1] / (D * D);      // 8
    const int nbuck = (N + 255) >> 8;         // 196

    const long long ND  = (long long)N * D;
    const long long RDD = (long long)R * D * D;
    const long long DDl = (long long)D * D;

    size_t off = 0;
    auto alloc = [&](size_t bytes) { size_t o = off; off = align256(off + bytes); return o; };
    size_t o_flag = alloc(256);
    size_t o_xc   = alloc((size_t)ND * 2);
    size_t o_W1   = alloc((size_t)RDD * 2);
    size_t o_lW1  = alloc((size_t)DDl * 2);
    size_t o_b1   = alloc((size_t)D * 2);
    size_t o_W2   = alloc((size_t)RDD * 2);
    size_t o_lW2  = alloc((size_t)DDl * 2);
    size_t o_b2   = alloc((size_t)D * 2);
    size_t o_h    = alloc((size_t)ND * 2);
    size_t o_offs = alloc((size_t)(N + 1) * 4);
    size_t o_gcnt = alloc(1024);
    size_t o_bst  = alloc(1040 * 4);
    size_t o_bcur = alloc(1024);
    size_t o_ebuf = alloc((size_t)E * 4);
    size_t o_ridx = alloc((size_t)E * 4);
    size_t o_wt   = alloc((size_t)2 * 9 * D * D * 2);  // fragment-ordered weights
    (void)ws_size;

    char* ws = (char*)d_ws;
    int* flag   = (int*)(ws + o_flag);
    u16* x_c    = (u16*)(ws + o_xc);
    u16* W1c    = (u16*)(ws + o_W1);
    u16* lW1c   = (u16*)(ws + o_lW1);
    u16* b1c    = (u16*)(ws + o_b1);
    u16* W2c    = (u16*)(ws + o_W2);
    u16* lW2c   = (u16*)(ws + o_lW2);
    u16* b2c    = (u16*)(ws + o_b2);
    u16* h      = (u16*)(ws + o_h);
    int* offs   = (int*)(ws + o_offs);
    int* gcnt   = (int*)(ws + o_gcnt);
    int* bstart = (int*)(ws + o_bst);
    int* bcur   = (int*)(ws + o_bcur);
    u32* ebuf   = (u32*)(ws + o_ebuf);
    int* rowidx = (int*)(ws + o_ridx);
    u16* wt     = (u16*)(ws + o_wt);

    dim3 blk(256, 1, 1);
    int mb    = (N + BM - 1) / BM;            // 3125 blocks
    int nblkE = (E + CH - 1) / CH;
    auto cdiv = [](long long n) { return (u32)((n + 255) / 256); };

    detect_dtype<<<dim3(1), blk, 0, stream>>>((const u16*)x_in, flag, gcnt, nbuck);
    long long tot = ND + RDD + DDl + D + RDD + DDl + D;
    to_bf16_all<<<dim3(cdiv(tot)), blk, 0, stream>>>(
        x_in, W1_in, lW1_in, b1_in, W2_in, lW2_in, b2_in,
        x_c, W1c, lW1c, b1c, W2c, lW2c, b2c,
        ND, RDD, DDl, (long long)D, RDD, DDl, (long long)D, flag);

    build_wt<<<dim3(18), blk, 0, stream>>>(
        W1c, (const u16*)W1_in, lW1c, (const u16*)lW1_in,
        W2c, (const u16*)W2_in, lW2c, (const u16*)lW2_in, flag, R, wt);

    // CSR build: (dst, et)-sorted edge lists
    csr_count<<<dim3(nblkE), blk, 0, stream>>>(dst, gcnt, E, nbuck);
    csr_scan<<<dim3(1), blk, 0, stream>>>(gcnt, bstart, bcur, nbuck, N, E, offs);
    csr_part<<<dim3(nblkE), blk, 0, stream>>>(src, dst, et, bcur, ebuf, E, N, nbuck);
    csr_emit<<<dim3(nbuck), blk, 0, stream>>>(ebuf, bstart, offs, rowidx, N);

    // layer 1: fused gather + deep GEMM (K=(R+1)*128), bias+relu
    rel_layer_fused<<<dim3(mb), dim3(512), 0, stream>>>(
        x_c, (const u16*)x_in, offs, rowidx, wt,
        b1c, (const u16*)b1_in, flag, N, R, 0, h);

    // layer 2: fused gather + deep GEMM, bias + row-L2-normalize
    rel_layer_fused<<<dim3(mb), dim3(512), 0, stream>>>(
        h, h, offs, rowidx, wt + (size_t)9 * D * D,
        b2c, (const u16*)b2_in, flag, N, R, 1, d_out);
}

// Round 5
// 284.791 us; speedup vs baseline: 2.2060x; 1.0699x over previous
//
#include <hip/hip_runtime.h>
#include <hip/hip_bf16.h>

#define D 128
#define CH 4096   // edges per block in CSR partition passes
#define BM 16     // dst rows per fused block (8 waves x 2 rows)

typedef unsigned int u32;
typedef unsigned short u16;
typedef __attribute__((ext_vector_type(8))) short s16x8;
typedef __attribute__((ext_vector_type(4))) float f32x4;
typedef __attribute__((ext_vector_type(2))) float f32x2;
typedef __attribute__((ext_vector_type(2))) u32 u32x2;

__device__ __forceinline__ float bf2f(u16 u) {
    union { u32 u; float f; } v; v.u = ((u32)u) << 16; return v.f;
}
__device__ __forceinline__ u16 f2bf(float f) {
    union { float f; u32 u; } v; v.f = f;
    return (u16)((v.u + 0x7fffu + ((v.u >> 16) & 1u)) >> 16);
}
__device__ __forceinline__ u32 pack_bf2(float a, float b) {
    __hip_bfloat162 t = __float22bfloat162_rn(make_float2(a, b));
    union { __hip_bfloat162 t; u32 u; } v; v.t = t; return v.u;
}
__device__ __forceinline__ void unpack2(u32 u, float& lo, float& hi) {
    union { u32 u; float f; } a, b;
    a.u = u << 16; b.u = u & 0xffff0000u;
    lo = a.f; hi = b.f;
}

// ---- dtype detector (also zeroes gcnt for the CSR build) ----
__global__ void detect_dtype(const u16* __restrict__ x, int* __restrict__ flag,
                             int* __restrict__ gcnt, int nbuck) {
    __shared__ int cnt;
    if (threadIdx.x == 0) cnt = 0;
    __syncthreads();
    if ((int)threadIdx.x < nbuck) gcnt[threadIdx.x] = 0;
    u16 u = x[2 * threadIdx.x];
    int e = (u >> 7) & 0xFF;
    if (e >= 96 && e <= 150) atomicAdd(&cnt, 1);
    __syncthreads();
    if (threadIdx.x == 0) *flag = (cnt >= 128) ? 0 : 1;
}

// ---- canonicalize x only (body runs when input is fp32); 4 elems/thread ----
__global__ __launch_bounds__(256)
void to_bf16_x(const float4* __restrict__ xin, u32x2* __restrict__ xout,
               long long n4, const int* __restrict__ flag)
{
    if (*flag == 0) return;
    long long i = (long long)blockIdx.x * 256 + threadIdx.x;
    if (i >= n4) return;
    float4 v = xin[i];
    u32x2 o;
    o[0] = pack_bf2(v.x, v.y);
    o[1] = pack_bf2(v.z, v.w);
    xout[i] = o;
}

// ==== bucketed CSR build: bucket = dst>>8 (needs N<=65536, src<2^16, et<8) ====
__global__ __launch_bounds__(256)
void csr_count(const int* __restrict__ dst, int* __restrict__ gcnt, int E, int nbuck) {
    __shared__ int scnt[256];
    int tid = threadIdx.x;
    scnt[tid] = 0;
    __syncthreads();
    int base = blockIdx.x * CH;
#pragma unroll
    for (int it = 0; it < CH / 256; ++it) {
        int e = base + it * 256 + tid;
        if (e < E) atomicAdd(&scnt[dst[e] >> 8], 1);
    }
    __syncthreads();
    if (tid < nbuck && scnt[tid] > 0) atomicAdd(&gcnt[tid], scnt[tid]);
}

__global__ __launch_bounds__(256)
void csr_scan(const int* __restrict__ gcnt, int* __restrict__ bstart, int* __restrict__ bcur,
              int nbuck, int N_, int E_, int* __restrict__ offs) {
    __shared__ int wpart[4];
    int tid = threadIdx.x, lane = tid & 63, wid = tid >> 6;
    int v = (tid < nbuck) ? gcnt[tid] : 0;
    int s = v;
#pragma unroll
    for (int off = 1; off < 64; off <<= 1) {
        int t = __shfl_up(s, off, 64);
        if (lane >= off) s += t;
    }
    if (lane == 63) wpart[wid] = s;
    __syncthreads();
    int add = 0;
    for (int w = 0; w < wid; ++w) add += wpart[w];
    int excl = add + s - v;
    if (tid <= nbuck) bstart[tid] = excl;
    if (tid < nbuck)  bcur[tid]  = excl;
    if (tid == 0) offs[N_] = E_;
}

// partition edges into bucket-contiguous ebuf; rec = (dst&255)<<24 | (et<<16) | src
__global__ __launch_bounds__(256)
void csr_part(const int* __restrict__ src, const int* __restrict__ dst,
              const int* __restrict__ et, int* __restrict__ bcur,
              u32* __restrict__ ebuf, int E, int N, int nbuck) {
    __shared__ int scnt[256], sbase[256];
    int tid = threadIdx.x;
    scnt[tid] = 0;
    __syncthreads();
    int base = blockIdx.x * CH;
#pragma unroll
    for (int it = 0; it < CH / 256; ++it) {
        int e = base + it * 256 + tid;
        if (e < E) atomicAdd(&scnt[dst[e] >> 8], 1);
    }
    __syncthreads();
    if (tid < nbuck) {
        int c = scnt[tid];
        sbase[tid] = c ? atomicAdd(&bcur[tid], c) : 0;
    }
    __syncthreads();
    scnt[tid] = 0;
    __syncthreads();
#pragma unroll
    for (int it = 0; it < CH / 256; ++it) {
        int e = base + it * 256 + tid;
        if (e >= E) continue;
        int d = dst[e];
        int b = d >> 8;
        int p = sbase[b] + atomicAdd(&scnt[b], 1);
        ebuf[p] = ((u32)(d & 255) << 24) | ((u32)et[e] << 16) | (u32)src[e];
    }
}

// one block per bucket: 2048-bin (dstlo*8 + et) counting sort -> offs + rowidx
// rowidx rec = (dst&31)<<19 | (et<<16) | src  -> rec>>16 is a (row,rel) flush key
__global__ __launch_bounds__(256)
void csr_emit(const u32* __restrict__ ebuf, const int* __restrict__ bstart,
              int* __restrict__ offs, int* __restrict__ rowidx, int N) {
    __shared__ int hist[2048], excl[2048], cur[2048];
    __shared__ int wpart[4];
    int b = blockIdx.x, tid = threadIdx.x;
    int lo = bstart[b], hi = bstart[b + 1];
    for (int i = tid; i < 2048; i += 256) { hist[i] = 0; cur[i] = 0; }
    __syncthreads();
    for (int i = lo + tid; i < hi; i += 256) {
        u32 rec = ebuf[i];
        int key = (int)((rec >> 24) << 3) | (int)((rec >> 16) & 7u);
        atomicAdd(&hist[key], 1);
    }
    __syncthreads();
    int loc[8]; int tsum = 0;
#pragma unroll
    for (int k = 0; k < 8; ++k) { loc[k] = tsum; tsum += hist[tid * 8 + k]; }
    int lane = tid & 63, wid = tid >> 6;
    int s = tsum;
#pragma unroll
    for (int off = 1; off < 64; off <<= 1) {
        int t = __shfl_up(s, off, 64);
        if (lane >= off) s += t;
    }
    if (lane == 63) wpart[wid] = s;
    __syncthreads();
    int add = 0;
    for (int w = 0; w < wid; ++w) add += wpart[w];
    int tex = add + s - tsum;
#pragma unroll
    for (int k = 0; k < 8; ++k) excl[tid * 8 + k] = tex + loc[k];
    int node = (b << 8) + tid;
    if (node < N) offs[node] = lo + tex;
    __syncthreads();
    for (int i = lo + tid; i < hi; i += 256) {
        u32 rec = ebuf[i];
        int key = (int)((rec >> 24) << 3) | (int)((rec >> 16) & 7u);
        int p = lo + excl[key] + atomicAdd(&cur[key], 1);
        rowidx[p] = (int)(((rec >> 24) & 31u) << 19) | (int)(rec & 0x7FFFFu);
    }
}

// ---- build W fragments from RAW inputs (dtype-aware):
// wt[layer][plane 0..8][wv:8][ks:4][lane:64][j:8] bf16
// element = W[k = ks*32 + (lane>>4)*8 + j][col = wv*16 + (lane&15)] ; plane 8 = loopW
__global__ __launch_bounds__(256)
void build_wt(const void* __restrict__ W1r, const void* __restrict__ lW1r,
              const void* __restrict__ W2r, const void* __restrict__ lW2r,
              const int* __restrict__ flag, int R_, u16* __restrict__ wt)
{
    bool f = (*flag != 0);
    int m = blockIdx.x;          // 0..17: layer = m/9, plane c = m%9
    int layer = m / 9, c = m % 9;
    size_t esz = f ? 4 : 2;
    const char* src;
    if (layer == 0) src = (c < R_) ? ((const char*)W1r + (size_t)c * D * D * esz) : (const char*)lW1r;
    else            src = (c < R_) ? ((const char*)W2r + (size_t)c * D * D * esz) : (const char*)lW2r;
    int tid = threadIdx.x;
    u16* dstp = wt + (size_t)m * 16384;
    for (int i = tid; i < 16384; i += 256) {
        int wvv = i >> 11;
        int ks  = (i >> 9) & 3;
        int ln  = (i >> 3) & 63;
        int j   = i & 7;
        int k   = ks * 32 + (ln >> 4) * 8 + j;
        int col = wvv * 16 + (ln & 15);
        int idx = k * 128 + col;
        dstp[i] = f ? f2bf(((const float*)src)[idx]) : ((const u16*)src)[idx];
    }
}

// ==== fused layer: BM=16 rows per block, 8 waves (each owns 2 contiguous rows) ====
// Phase 1 (gather): unified (row,rel)-keyed linear scan over the wave's contiguous
//   edge range. Edges are (dst,et)-sorted; rowidx rec>>16 = (dst&31)<<3|et is the
//   flush key -> one scalar compare per edge, rolling f32 accumulator, flush to
//   bf16 LDS plane [rel][row][128] (XOR chunk swizzle) on key change.
//   Self plane staged via global_load_lds with pre-swizzled source.
// Phase 2: C[16x128] = sum_c planes[c] @ W_c (K=(R+1)*128); wave wv owns 16 cols.
// mode 0: +bias, relu, bf16. mode 1: +bias, row-L2-normalize, f32/bf16 out.
__global__ __launch_bounds__(512, 8)
void rel_layer_fused(const u16* __restrict__ xc, const u16* __restrict__ xo,
                     const int* __restrict__ offs, const int* __restrict__ rowidx,
                     const u16* __restrict__ wt,
                     const void* __restrict__ bias_raw,
                     const int* __restrict__ flag,
                     int M, int R_, int mode, void* __restrict__ out)
{
    __shared__ u16 As[9 * BM * D];   // 36864 B -> 4 blocks/CU (32 waves/CU)
    const bool f = (*flag != 0);
    const u16* X = f ? xc : xo;

    const int row0 = blockIdx.x * BM;
    const int tid  = threadIdx.x;
    const int lane = tid & 63;
    const int wv   = tid >> 6;        // 0..7
    const int quad = lane >> 4;
    const int l16  = lane & 15;

    // ---- stage self plane (plane 8): waves 0..3, 4 rows each ----
    if (wv < 4) {
        auto* lds0 = (__attribute__((address_space(3))) char*)As;
        int rl = wv * 4 + quad;
        int rg = row0 + rl; if (rg >= M) rg = M - 1;
        int cg = l16 ^ rl;            // pre-swizzled source chunk
        const u16* gp = X + (size_t)rg * D + cg * 8;
        __builtin_amdgcn_global_load_lds(
            (const __attribute__((address_space(1))) void*)gp,
            (__attribute__((address_space(3))) void*)(lds0 + 8 * BM * 256 + wv * 1024),
            16, 0, 0);
    }

    // ---- zero this wave's 2 rows across the 8 relation planes ----
    {
        u32* pz = (u32*)As;
        int rbase = wv * 2;
#pragma unroll
        for (int pl = 0; pl < 8; ++pl)
#pragma unroll
            for (int rr = 0; rr < 2; ++rr)
                pz[(pl * BM + rbase + rr) * 64 + lane] = 0;
    }

    // ---- gather phase: unified-key linear scan over the wave's edge range ----
    {
        const u32* X32 = (const u32*)X;   // row stride 64 u32
        u32* plane = (u32*)As;
        int rA = row0 + wv * 2;
        int i0 = rA < M ? rA : M;
        int i1 = rA + 2 < M ? rA + 2 : M;
        int j0 = offs[i0], j1 = offs[i1];   // contiguous range for 2 rows
        int key = -1;
        float a0 = 0.f, a1 = 0.f;
        int base = j0;
        while (base < j1) {
            int wlen = j1 - base; if (wlen > 64) wlen = 64;
            int vrec = rowidx[base + (lane < wlen ? lane : wlen - 1)];
            for (int pos = 0; pos < wlen; pos += 16) {
                int nb = wlen - pos; if (nb > 16) nb = 16;
                int sr[16]; u32 g[16];
#pragma unroll
                for (int k = 0; k < 16; ++k)
                    if (k < nb) sr[k] = __builtin_amdgcn_readlane(vrec, pos + k);
#pragma unroll
                for (int k = 0; k < 16; ++k)
                    if (k < nb) g[k] = (X32 + ((u32)(sr[k] & 0xffff) << 6))[lane];
#pragma unroll
                for (int k = 0; k < 16; ++k) {
                    if (k < nb) {
                        int nk = sr[k] >> 16;
                        if (nk != key) {          // row or relation boundary: flush
                            if (key >= 0) {
                                int rl = ((key >> 3) - row0) & 31;
                                int vsw = (((lane >> 2) ^ rl) << 2) | (lane & 3);
                                plane[((key & 7) * BM + rl) * 64 + vsw] = pack_bf2(a0, a1);
                            }
                            key = nk; a0 = 0.f; a1 = 0.f;
                        }
                        float lo_, hi_;
                        unpack2(g[k], lo_, hi_);
                        a0 += lo_; a1 += hi_;
                    }
                }
            }
            base += wlen;
        }
        if (key >= 0) {
            int rl = ((key >> 3) - row0) & 31;
            int vsw = (((lane >> 2) ^ rl) << 2) | (lane & 3);
            plane[((key & 7) * BM + rl) * 64 + vsw] = pack_bf2(a0, a1);
        }
    }

    __syncthreads();   // drains global_load_lds + LDS writes

    // ---- MFMA phase: wave wv computes rows 0..15 x cols [wv*16, wv*16+16) ----
    f32x4 acc = (f32x4)0.f;
    for (int c = 0; c <= R_; ++c) {
        int cidx = (c < R_) ? c : 8;
        const u16* Bt = wt + (size_t)cidx * 16384 + (size_t)wv * 2048 + lane * 8;
        s16x8 bfr[4];
#pragma unroll
        for (int ks = 0; ks < 4; ++ks)
            bfr[ks] = *(const s16x8*)(Bt + ks * 512);
#pragma unroll
        for (int ks = 0; ks < 4; ++ks) {
            int chp = (ks * 4 + quad) ^ l16;
            s16x8 a = *(const s16x8*)(As + (cidx * BM + l16) * D + chp * 8);
            acc = __builtin_amdgcn_mfma_f32_16x16x32_bf16(a, bfr[ks], acc, 0, 0, 0);
        }
    }

    const int col = wv * 16 + l16;     // 0..127
    const float b = f ? ((const float*)bias_raw)[col]
                      : bf2f(((const u16*)bias_raw)[col]);

    if (mode == 0) {
        u32* o = (u32*)out;
#pragma unroll
        for (int i = 0; i < 4; ++i) {
            int r = row0 + quad * 4 + i;
            float v = fmaxf(acc[i] + b, 0.f);
            float vp = __shfl_xor(v, 1, 64);
            if (!(l16 & 1) && r < M)
                o[(size_t)r * 64 + (col >> 1)] = pack_bf2(v, vp);
        }
    } else {
        float v[4];
        float pr[4];
#pragma unroll
        for (int i = 0; i < 4; ++i) {
            v[i] = acc[i] + b;
            float p = v[i] * v[i];
            p += __shfl_xor(p, 1, 64);
            p += __shfl_xor(p, 2, 64);
            p += __shfl_xor(p, 4, 64);
            p += __shfl_xor(p, 8, 64);
            pr[i] = p;                 // this wave's 16-col partial for row quad*4+i
        }
        __syncthreads();               // planes no longer needed: reuse as scratch
        float* fs = (float*)As;        // fs[row*8 + wv], scales at fs[128..143]
        if (l16 == 0) {
#pragma unroll
            for (int i = 0; i < 4; ++i) fs[(quad * 4 + i) * 8 + wv] = pr[i];
        }
        __syncthreads();
        if (tid < 16) {
            float s = 0.f;
#pragma unroll
            for (int w = 0; w < 8; ++w) s += fs[tid * 8 + w];
            fs[128 + tid] = 1.f / fmaxf(sqrtf(s), 1e-12f);
        }
        __syncthreads();
#pragma unroll
        for (int i = 0; i < 4; ++i) {
            int rl = quad * 4 + i;
            int r = row0 + rl;
            float sc = fs[128 + rl];
            float a0 = v[i] * sc;
            float ap = __shfl_xor(a0, 1, 64);
            if (!(l16 & 1) && r < M) {
                if (f) {
                    f32x2 w; w[0] = a0; w[1] = ap;
                    ((f32x2*)out)[(size_t)r * 64 + (col >> 1)] = w;
                } else {
                    ((u32*)out)[(size_t)r * 64 + (col >> 1)] = pack_bf2(a0, ap);
                }
            }
        }
    }
}

static inline size_t align256(size_t x) { return (x + 255) & ~(size_t)255; }

extern "C" void kernel_launch(void* const* d_in, const int* in_sizes, int n_in,
                              void* d_out, int out_size, void* d_ws, size_t ws_size,
                              hipStream_t stream)
{
    const void* x_in   = d_in[0];
    const void* W1_in  = d_in[1];
    const void* lW1_in = d_in[2];
    const void* b1_in  = d_in[3];
    const void* W2_in  = d_in[4];
    const void* lW2_in = d_in[5];
    const void* b2_in  = d_in[6];
    const int* src = (const int*)d_in[7];
    const int* dst = (const int*)d_in[8];
    const int* et  = (const int*)d_in[9];

    const int N = in_sizes[0] / D;            // 50000
    const int E = in_sizes[7];                // 800000
    const int R = in_sizes[1] / (D * D);      // 8
    const int nbuck = (N + 255) >> 8;         // 196

    const long long ND = (long long)N * D;

    size_t off = 0;
    auto alloc = [&](size_t bytes) { size_t o = off; off = align256(off + bytes); return o; };
    size_t o_flag = alloc(256);
    size_t o_xc   = alloc((size_t)ND * 2);
    size_t o_h    = alloc((size_t)ND * 2);
    size_t o_offs = alloc((size_t)(N + 1) * 4);
    size_t o_gcnt = alloc(1024);
    size_t o_bst  = alloc(1040 * 4);
    size_t o_bcur = alloc(1024);
    size_t o_ebuf = alloc((size_t)E * 4);
    size_t o_ridx = alloc((size_t)E * 4);
    size_t o_wt   = alloc((size_t)2 * 9 * D * D * 2);  // fragment-ordered weights
    (void)ws_size;

    char* ws = (char*)d_ws;
    int* flag   = (int*)(ws + o_flag);
    u16* x_c    = (u16*)(ws + o_xc);
    u16* h      = (u16*)(ws + o_h);
    int* offs   = (int*)(ws + o_offs);
    int* gcnt   = (int*)(ws + o_gcnt);
    int* bstart = (int*)(ws + o_bst);
    int* bcur   = (int*)(ws + o_bcur);
    u32* ebuf   = (u32*)(ws + o_ebuf);
    int* rowidx = (int*)(ws + o_ridx);
    u16* wt     = (u16*)(ws + o_wt);

    dim3 blk(256, 1, 1);
    int mb    = (N + BM - 1) / BM;            // 3125 blocks
    int nblkE = (E + CH - 1) / CH;

    detect_dtype<<<dim3(1), blk, 0, stream>>>((const u16*)x_in, flag, gcnt, nbuck);

    long long n4 = ND / 4;
    to_bf16_x<<<dim3((u32)((n4 + 255) / 256)), blk, 0, stream>>>(
        (const float4*)x_in, (u32x2*)x_c, n4, flag);

    build_wt<<<dim3(18), blk, 0, stream>>>(
        W1_in, lW1_in, W2_in, lW2_in, flag, R, wt);

    // CSR build: (dst, et)-sorted edge lists
    csr_count<<<dim3(nblkE), blk, 0, stream>>>(dst, gcnt, E, nbuck);
    csr_scan<<<dim3(1), blk, 0, stream>>>(gcnt, bstart, bcur, nbuck, N, E, offs);
    csr_part<<<dim3(nblkE), blk, 0, stream>>>(src, dst, et, bcur, ebuf, E, N, nbuck);
    csr_emit<<<dim3(nbuck), blk, 0, stream>>>(ebuf, bstart, offs, rowidx, N);

    // layer 1: fused gather + deep GEMM (K=(R+1)*128), bias+relu
    rel_layer_fused<<<dim3(mb), dim3(512), 0, stream>>>(
        x_c, (const u16*)x_in, offs, rowidx, wt,
        b1_in, flag, N, R, 0, h);

    // layer 2: fused gather + deep GEMM, bias + row-L2-normalize
    rel_layer_fused<<<dim3(mb), dim3(512), 0, stream>>>(
        h, h, offs, rowidx, wt + (size_t)9 * D * D,
        b2_in, flag, N, R, 1, d_out);
}